// Round 16
// baseline (197.271 us; speedup 1.0000x reference)
//
#include <hip/hip_runtime.h>
#include <hip/hip_bf16.h>

// ---------------------------------------------------------------------------
// SelfAttention fused pipeline for MI355X (gfx950)
//   x(4,1024,2048) f32; Wq(2048,2048) Wk/Wv(2048,512) Wp(2048,2048) f32
//   QKV GEMM (256x256 8-phase) writes f32 Q/K (coalesced, like proj) +
//   bf16 transposed V; rope kernel reads f32, applies table RoPE, writes
//   bf16 qb/kb; attention in bf16 MFMA, no-max log2-domain softmax.
//   R16: Q/K epilogue f32 (proj-style coalesced dword stores) — the scalar
//   bf16 store epilogue was costing ~2x per-CU GEMM rate vs proj.
// ---------------------------------------------------------------------------

typedef __attribute__((ext_vector_type(4))) float f32x4;
typedef __attribute__((ext_vector_type(8))) short short8;

#define AS1C(p) ((const __attribute__((address_space(1))) void*)(p))
#define AS3(p)  ((__attribute__((address_space(3))) void*)(p))

__device__ __forceinline__ unsigned short f2bf(float f) {
  union { float f; unsigned int u; } x; x.f = f;
  unsigned int r = x.u + 0x7FFFu + ((x.u >> 16) & 1u);  // round-to-nearest-even
  return (unsigned short)(r >> 16);
}

__device__ __forceinline__ unsigned short bfc(float f) {
  return __bfloat16_as_ushort(__float2bfloat16(f));  // HW cvt
}

// native 2^x (v_exp_f32): 1 VALU op; 2^(-inf)=+0
__device__ __forceinline__ float ex2(float x) {
  return __builtin_amdgcn_exp2f(x);
}

// -------------------- RoPE table: tab[t*32+i] = (cos, sin) ------------------
__global__ void rope_tab_kernel(float2* __restrict__ tab) {
  const int idx = blockIdx.x * 256 + threadIdx.x;  // 32768
  const int t = idx >> 5, i = idx & 31;
  const float invf = exp2f(-(float)i * 0.41524101186092029f);
  float sv, cv;
  __sincosf((float)t * invf, &sv, &cv);
  tab[idx] = make_float2(cv, sv);
}

// -------------------- x : f32 -> bf16 (vectorized) -------------------------
__global__ void cvt_bf16_kernel(const float* __restrict__ src,
                                unsigned short* __restrict__ dst, int n4) {
  int i = blockIdx.x * blockDim.x + threadIdx.x;
  if (i >= n4) return;
  const f32x4 v = *(const f32x4*)(src + (size_t)i * 4);
  ushort4 u = make_ushort4(f2bf(v[0]), f2bf(v[1]), f2bf(v[2]), f2bf(v[3]));
  *(ushort4*)(dst + (size_t)i * 4) = u;
}

// ---- fused W transpose for Wq|Wk|Wv -> Wt [3072][2048], z selects matrix ---
__global__ void transpose_qkv_w_kernel(const float* __restrict__ Wq,
                                       const float* __restrict__ Wk,
                                       const float* __restrict__ Wv,
                                       unsigned short* __restrict__ dst) {
  __shared__ float tile[32][33];
  const int z = blockIdx.z;
  const float* src;
  int N, rowOff;
  float scale;
  if (z == 0)      { src = Wq; N = 2048; rowOff = 0;    scale = 0.18033688011112042f; }
  else if (z == 1) { src = Wk; N = 512;  rowOff = 2048; scale = 1.0f; }
  else             { src = Wv; N = 512;  rowOff = 2560; scale = 1.0f; }
  const int n0 = blockIdx.x * 32, k0 = blockIdx.y * 32;
  if (n0 >= N) return;
  const int tx = threadIdx.x & 31, ty = threadIdx.x >> 5;  // 32x8
#pragma unroll
  for (int i = ty; i < 32; i += 8)
    tile[i][tx] = src[(size_t)(k0 + i) * N + (n0 + tx)];
  __syncthreads();
#pragma unroll
  for (int i = ty; i < 32; i += 8)
    dst[(size_t)(rowOff + n0 + i) * 2048 + (k0 + tx)] = f2bf(tile[tx][i] * scale);
}

// -- W transpose+convert: dst[(rowOff+n)*2048+k] = bf16(src[k*N+n]*s) --------
__global__ void transpose_bf16_kernel(const float* __restrict__ src,
                                      unsigned short* __restrict__ dst,
                                      int N, int rowOff, float scale) {
  __shared__ float tile[32][33];
  const int n0 = blockIdx.x * 32, k0 = blockIdx.y * 32;
  const int tx = threadIdx.x & 31, ty = threadIdx.x >> 5;  // 32x8
#pragma unroll
  for (int i = ty; i < 32; i += 8)
    tile[i][tx] = src[(size_t)(k0 + i) * N + (n0 + tx)];
  __syncthreads();
#pragma unroll
  for (int i = ty; i < 32; i += 8)
    dst[(size_t)(rowOff + n0 + i) * 2048 + (k0 + tx)] = f2bf(tile[tx][i] * scale);
}

// ---- wide RoPE: reads qkf f32 [4096][2560], writes bf16 qb/kb --------------
__global__ void rope_cvt2_kernel(const float2* __restrict__ tab,
                                 const float* __restrict__ qkf,
                                 unsigned short* __restrict__ qb,
                                 unsigned short* __restrict__ kb) {
  const int idx = blockIdx.x * 256 + threadIdx.x;  // 4096*320
  const int m = idx / 320;
  const int p = idx - m * 320;
  const int t = m & 1023;
  unsigned short* dst;
  int srcCol, dcol;
  if (p < 256) { dcol = p * 8; srcCol = dcol; dst = qb + (size_t)m * 2048 + dcol; }
  else         { dcol = (p - 256) * 8; srcCol = 2048 + dcol; dst = kb + (size_t)m * 512 + dcol; }
  const int i0 = (srcCol & 63) >> 1;
  const float* src = qkf + (size_t)m * 2560 + srcCol;
  const f32x4 v0 = *(const f32x4*)(src);
  const f32x4 v1 = *(const f32x4*)(src + 4);
  float x[8] = {v0[0], v0[1], v0[2], v0[3], v1[0], v1[1], v1[2], v1[3]};
  short8 o;
#pragma unroll
  for (int j = 0; j < 4; ++j) {
    const float2 cs = tab[t * 32 + i0 + j];
    const float x1 = x[2 * j], x2 = x[2 * j + 1];
    o[2 * j]     = (short)bfc(x1 * cs.x - x2 * cs.y);
    o[2 * j + 1] = (short)bfc(x2 * cs.x + x1 * cs.y);
  }
  *(short8*)dst = o;
}

// ======================= shared 256x256 8-phase GEMM core ===================
// 512 thr (8 waves), BK=64, 2 K-tiles/iter; counted vmcnt 6@P4 / 8@P8;
// granule-XOR swizzle both-sides (rule #21); XCD-chunked block swizzle (T1).
#define GEMM_CORE(A_, Bt_, K_)                                                           \
  __shared__ unsigned short S[65536];                                                    \
  const int tid = threadIdx.x;                                                           \
  const int lane = tid & 63, w = tid >> 6;                                               \
  const int l15 = lane & 15, lg = lane >> 4;                                             \
  const int nwgx = gridDim.x;                                                            \
  const int nwg = nwgx * gridDim.y;                                                      \
  int lid = blockIdx.x + nwgx * blockIdx.y;                                              \
  lid = (lid & 7) * (nwg >> 3) + (lid >> 3);                                             \
  const int m0 = (lid / nwgx) * 256, n0 = (lid % nwgx) * 256;                            \
  const int ah = w >> 2;                                                                 \
  const int bh = (w & 3) >> 1;                                                           \
  const int bs = (w & 1) * 64;                                                           \
  const int NT = (K_) >> 6;                                                              \
  const int sr = tid >> 3;                                                               \
  const int sc = ((tid & 7) ^ (sr & 7)) << 3;                                            \
  f32x4 acc[8][4];                                                                       \
  _Pragma("unroll") for (int i = 0; i < 8; ++i)                                          \
  _Pragma("unroll") for (int j = 0; j < 4; ++j)                                          \
  _Pragma("unroll") for (int c = 0; c < 4; ++c) acc[i][j][c] = 0.f;                      \
  SB(0, 0); SB(0, 1); SA(0, 0); SA(0, 1);                                                \
  SB(1, 0); SB(1, 1); SA(1, 0); SA(1, 1);                                                \
  asm volatile("s_waitcnt vmcnt(8)" ::: "memory");                                       \
  __builtin_amdgcn_s_barrier();                                                          \
  short8 af[2][4], b0[2][2], b1[2][2];                                                   \
  for (int t = 0; t < NT; t += 2) {                                                      \
    const bool nl = (t + 2 < NT);                                                        \
    RDA(t, 0); RDB(b0, t, 0);                                                            \
    BAR();                                                                               \
    MM(0, 0, b0);                                                                        \
    BAR();                                                                               \
    RDB(b1, t, 1);                                                                       \
    BAR();                                                                               \
    MM(0, 1, b1);                                                                        \
    BAR();                                                                               \
    RDA(t, 1);                                                                           \
    if (nl) SB(t + 2, 0);                                                                \
    BAR();                                                                               \
    MM(1, 1, b1);                                                                        \
    BAR();                                                                               \
    if (nl) {                                                                            \
      SB(t + 2, 1); SA(t + 2, 0);                                                        \
      asm volatile("s_waitcnt vmcnt(6)" ::: "memory");                                   \
    } else {                                                                             \
      asm volatile("s_waitcnt vmcnt(0)" ::: "memory");                                   \
    }                                                                                    \
    BAR();                                                                               \
    MM(1, 0, b0);                                                                        \
    BAR();                                                                               \
    RDA(t + 1, 0); RDB(b0, t + 1, 0);                                                    \
    if (nl) SA(t + 2, 1);                                                                \
    BAR();                                                                               \
    MM(0, 0, b0);                                                                        \
    BAR();                                                                               \
    RDB(b1, t + 1, 1);                                                                   \
    BAR();                                                                               \
    MM(0, 1, b1);                                                                        \
    BAR();                                                                               \
    RDA(t + 1, 1);                                                                       \
    if (nl) SB(t + 3, 0);                                                                \
    BAR();                                                                               \
    MM(1, 1, b1);                                                                        \
    BAR();                                                                               \
    if (nl) {                                                                            \
      SB(t + 3, 1); SA(t + 3, 0); SA(t + 3, 1);                                          \
      asm volatile("s_waitcnt vmcnt(8)" ::: "memory");                                   \
    }                                                                                    \
    BAR();                                                                               \
    MM(1, 0, b0);                                                                        \
    BAR();                                                                               \
  }

#define SA(tile, half)                                                                   \
  do {                                                                                   \
    const unsigned short* p_ = Ap + (size_t)(m0 + (half) * 128 + sr) * Kd + (tile) * 64 + sc; \
    const int d_ = (((tile) & 1) << 14) + ((half) << 13) + tid * 8;                      \
    __builtin_amdgcn_global_load_lds(AS1C(p_), AS3(&S[d_]), 16, 0, 0);                   \
    __builtin_amdgcn_global_load_lds(AS1C(p_ + (size_t)64 * Kd), AS3(&S[d_ + 4096]), 16, 0, 0); \
  } while (0)

#define SB(tile, half)                                                                   \
  do {                                                                                   \
    const unsigned short* p_ = Bp + (size_t)(n0 + (half) * 128 + sr) * Kd + (tile) * 64 + sc; \
    const int d_ = 32768 + (((tile) & 1) << 14) + ((half) << 13) + tid * 8;              \
    __builtin_amdgcn_global_load_lds(AS1C(p_), AS3(&S[d_]), 16, 0, 0);                   \
    __builtin_amdgcn_global_load_lds(AS1C(p_ + (size_t)64 * Kd), AS3(&S[d_ + 4096]), 16, 0, 0); \
  } while (0)

#define RDA(tile, Msub)                                                                  \
  _Pragma("unroll") for (int kk = 0; kk < 2; ++kk)                                       \
  _Pragma("unroll") for (int fm = 0; fm < 4; ++fm) {                                     \
    const int r_ = (Msub) * 64 + fm * 16 + l15;                                          \
    af[kk][fm] = *(const short8*)&S[(((tile) & 1) << 14) + (ah << 13) + r_ * 64 +        \
                                    (((kk << 2) | lg) ^ (r_ & 7)) * 8];                  \
  }

#define RDB(dst, tile, Nsub)                                                             \
  _Pragma("unroll") for (int kk = 0; kk < 2; ++kk)                                       \
  _Pragma("unroll") for (int j = 0; j < 2; ++j) {                                        \
    const int r_ = bs + ((Nsub) * 2 + j) * 16 + l15;                                     \
    dst[kk][j] = *(const short8*)&S[32768 + (((tile) & 1) << 14) + (bh << 13) + r_ * 64 +\
                                    (((kk << 2) | lg) ^ (r_ & 7)) * 8];                  \
  }

#define MM(Msub, Nsub, bb)                                                               \
  do {                                                                                   \
    __builtin_amdgcn_s_setprio(1);                                                       \
    _Pragma("unroll") for (int kk = 0; kk < 2; ++kk)                                     \
    _Pragma("unroll") for (int fm = 0; fm < 4; ++fm)                                     \
    _Pragma("unroll") for (int j = 0; j < 2; ++j)                                        \
      acc[(Msub) * 4 + fm][(Nsub) * 2 + j] = __builtin_amdgcn_mfma_f32_16x16x32_bf16(    \
          af[kk][fm], bb[kk][j], acc[(Msub) * 4 + fm][(Nsub) * 2 + j], 0, 0, 0);         \
    __builtin_amdgcn_s_setprio(0);                                                       \
  } while (0)

#define BAR() __builtin_amdgcn_s_barrier()

// ---------------- plain GEMM (used for the output projection) --------------
__global__ __launch_bounds__(512, 2) void gemm256_kernel(
    const unsigned short* __restrict__ Ap, const unsigned short* __restrict__ Bp,
    float* __restrict__ C, int K, int N) {
  const int Kd = K;
  GEMM_CORE(Ap, Bp, Kd)
#pragma unroll
  for (int fm8 = 0; fm8 < 8; ++fm8)
#pragma unroll
    for (int fn4 = 0; fn4 < 4; ++fn4) {
      const size_t base =
          (size_t)(m0 + ah * 128 + (fm8 >> 2) * 64 + (fm8 & 3) * 16 + lg * 4) * N +
          (n0 + (w & 3) * 64 + fn4 * 16 + l15);
#pragma unroll
      for (int r = 0; r < 4; ++r) C[base + (size_t)r * N] = acc[fm8][fn4][r];
    }
}

// ---------- QKV GEMM: f32 Q/K (coalesced) + bf16 V^T ------------------------
// cols <2560: -> qkf[4096][2560] f32 (proj-style coalesced dword stores)
// else:       -> vt[(b*8+kvh)*64+d][1024] bf16 (packed ushort4 transposed)
__global__ __launch_bounds__(512, 2) void gemm256_qkv_kernel(
    const unsigned short* __restrict__ Ap, const unsigned short* __restrict__ Bp,
    float* __restrict__ qkf, unsigned short* __restrict__ vt) {
  const int Kd = 2048;
  GEMM_CORE(Ap, Bp, Kd)

  const int colbase = n0 + (w & 3) * 64;
  if (n0 >= 2560) {
    // ---- V region: direct transposed bf16 store (4 t-values packed) ----
#pragma unroll
    for (int fm8 = 0; fm8 < 8; ++fm8) {
      const int row = m0 + ah * 128 + (fm8 >> 2) * 64 + (fm8 & 3) * 16 + lg * 4;
      const int z = (row >> 10) * 8 + ((colbase - 2560) >> 6);
      const int t0 = row & 1023;
#pragma unroll
      for (int fn4 = 0; fn4 < 4; ++fn4) {
        const int d = (colbase + fn4 * 16 + l15 - 2560) & 63;
        ushort4 u = make_ushort4(bfc(acc[fm8][fn4][0]), bfc(acc[fm8][fn4][1]),
                                 bfc(acc[fm8][fn4][2]), bfc(acc[fm8][fn4][3]));
        *(ushort4*)&vt[(size_t)z * 65536 + d * 1024 + t0] = u;
      }
    }
  } else {
    // ---- Q/K region: coalesced f32 stores (rope+cast done downstream) ----
#pragma unroll
    for (int fm8 = 0; fm8 < 8; ++fm8) {
      const int row = m0 + ah * 128 + (fm8 >> 2) * 64 + (fm8 & 3) * 16 + lg * 4;
#pragma unroll
      for (int fn4 = 0; fn4 < 4; ++fn4) {
        const size_t base = (size_t)row * 2560 + colbase + fn4 * 16 + l15;
#pragma unroll
        for (int r = 0; r < 4; ++r) qkf[base + (size_t)r * 2560] = acc[fm8][fn4][r];
      }
    }
  }
}

// -------------------- bf16 MFMA flash attention (causal, GQA 4:1) -----------
// XCD-chunked swizzle: 8 consecutive work ids share one (h,b) K/V pair.
// block: (bx, h, b); TWO q-tiles {bx, 15-bx} -> uniform 17 KV-tiles/block.
// 4 waves; dbuf K/V; ones-column MFMA row-sum; NO-max softmax (P = 2^sa).
__global__ __launch_bounds__(256) void attn_mfma_kernel(
    const unsigned short* __restrict__ qb, const unsigned short* __restrict__ kb,
    const unsigned short* __restrict__ vt, unsigned short* __restrict__ attnb) {
  int lid = blockIdx.x + 8 * (blockIdx.y + 32 * blockIdx.z);  // 1024 blocks
  lid = (lid & 7) * 128 + (lid >> 3);                         // bijective chunk
  const int bx = lid & 7, h = (lid >> 3) & 31, b = lid >> 8;
  const int kvh = h >> 2;
  __shared__ unsigned short S[20480];  // 40 KiB
  const int tid = threadIdx.x, lane = tid & 63, w = tid >> 6;
  const int l15 = lane & 15, lg = lane >> 4;
  const int rowbase = w * 16 + lg * 4;

  const int gi0 = w * 64 + lane;
  const int r0 = gi0 >> 3, g0 = (gi0 & 7) ^ (r0 & 7);
  const int gi1 = (4 + w) * 64 + lane;
  const int r1 = gi1 >> 3, g1 = (gi1 & 7) ^ (r1 & 7);

  const unsigned short* kbase = kb + (size_t)b * 1024 * 512 + kvh * 64;
  const unsigned short* vbase = vt + (size_t)(b * 8 + kvh) * 64 * 1024;

#define STAGE_KV(kOff, vOff, jj)                                                    \
  do {                                                                              \
    __builtin_amdgcn_global_load_lds(AS1C(kbase + ((jj) * 64 + r0) * 512 + g0 * 8), \
                                     AS3(&S[(kOff) + w * 512]), 16, 0, 0);          \
    __builtin_amdgcn_global_load_lds(AS1C(kbase + ((jj) * 64 + r1) * 512 + g1 * 8), \
                                     AS3(&S[(kOff) + (4 + w) * 512]), 16, 0, 0);    \
    __builtin_amdgcn_global_load_lds(AS1C(vbase + r0 * 1024 + (jj) * 64 + g0 * 8),  \
                                     AS3(&S[(vOff) + w * 512]), 16, 0, 0);          \
    __builtin_amdgcn_global_load_lds(AS1C(vbase + r1 * 1024 + (jj) * 64 + g1 * 8),  \
                                     AS3(&S[(vOff) + (4 + w) * 512]), 16, 0, 0);    \
  } while (0)

#define STAGE_Q(qt)                                                                     \
  do {                                                                                  \
    const size_t qr_ = (size_t)b * 1024 + (qt) * 64;                                    \
    __builtin_amdgcn_global_load_lds(AS1C(qb + (qr_ + r0) * 2048 + h * 64 + g0 * 8),    \
                                     AS3(&S[w * 512]), 16, 0, 0);                       \
    __builtin_amdgcn_global_load_lds(AS1C(qb + (qr_ + r1) * 2048 + h * 64 + g1 * 8),    \
                                     AS3(&S[(4 + w) * 512]), 16, 0, 0);                 \
  } while (0)

  const int qts0 = bx, qts1 = 15 - bx;

  short8 ones;
#pragma unroll
  for (int i = 0; i < 8; ++i) ones[i] = (short)0x3F80;  // bf16 1.0

  STAGE_Q(qts0);
  STAGE_KV(4096, 12288, 0);
  __syncthreads();

  int g = 0;
  for (int sub = 0; sub < 2; ++sub) {
    const int qtc = sub ? qts1 : qts0;
    const size_t qrow0 = (size_t)b * 1024 + qtc * 64;

    short8 qf[2];
#pragma unroll
    for (int kk = 0; kk < 2; ++kk) {
      const int r = w * 16 + l15;
      const int gq = ((kk << 2) | lg) ^ (r & 7);
      qf[kk] = *(const short8*)&S[r * 64 + gq * 8];
    }

    f32x4 oa[4], oe;
#pragma unroll
    for (int r = 0; r < 4; ++r) oe[r] = 0.f;
#pragma unroll
    for (int fd = 0; fd < 4; ++fd)
#pragma unroll
      for (int r = 0; r < 4; ++r) oa[fd][r] = 0.f;

    for (int j = 0; j <= qtc; ++j, ++g) {
      const int cur = g & 1;
      const int kOff = 4096 + cur * 4096;
      const int vOff = 12288 + cur * 4096;
      if (g < 16) {
        const int nj = (g + 1 <= qts0) ? g + 1 : g - qts0;
        STAGE_KV(4096 + (cur ^ 1) * 4096, 12288 + (cur ^ 1) * 4096, nj);
      }

      f32x4 sa[4];
#pragma unroll
      for (int fn = 0; fn < 4; ++fn)
#pragma unroll
        for (int r = 0; r < 4; ++r) sa[fn][r] = 0.f;
#pragma unroll
      for (int kk = 0; kk < 2; ++kk) {
        short8 kf[4];
#pragma unroll
        for (int fn = 0; fn < 4; ++fn) {
          const int rkv = fn * 16 + l15;
          const int gk = ((kk << 2) | lg) ^ (rkv & 7);
          kf[fn] = *(const short8*)&S[kOff + rkv * 64 + gk * 8];
        }
        __builtin_amdgcn_s_setprio(1);
#pragma unroll
        for (int fn = 0; fn < 4; ++fn)
          sa[fn] = __builtin_amdgcn_mfma_f32_16x16x32_bf16(qf[kk], kf[fn], sa[fn], 0, 0, 0);
        __builtin_amdgcn_s_setprio(0);
      }

      // ---- no-max softmax: P = 2^sa (masked -> 2^-inf = 0) ----
      if (j == qtc) {
#pragma unroll
        for (int r = 0; r < 4; ++r) {
          const int row = rowbase + r;
#pragma unroll
          for (int fn = 0; fn < 4; ++fn)
            if ((fn * 16 + l15) > row) sa[fn][r] = -INFINITY;
        }
      }
#pragma unroll
      for (int fn = 0; fn < 4; ++fn)
#pragma unroll
        for (int r = 0; r < 4; ++r) sa[fn][r] = ex2(sa[fn][r]);

      // ---- P -> LDS (bf16, swizzled; wave-private band in QP) ----
#pragma unroll
      for (int r = 0; r < 4; ++r) {
        const int prow = rowbase + r;
#pragma unroll
        for (int fn = 0; fn < 4; ++fn) {
          const int col = fn * 16 + l15;
          const int gp = (col >> 3) ^ (prow & 7);
          S[prow * 64 + gp * 8 + (col & 7)] = bfc(sa[fn][r]);
        }
      }

      // ---- O += P V ; row-sum += P * 1 ----
#pragma unroll
      for (int kk = 0; kk < 2; ++kk) {
        const int rp = w * 16 + l15;
        const int gp = ((kk << 2) | lg) ^ (rp & 7);
        const short8 pf = *(const short8*)&S[rp * 64 + gp * 8];
        short8 vf[4];
#pragma unroll
        for (int fd = 0; fd < 4; ++fd) {
          const int rd = fd * 16 + l15;
          const int gv = ((kk << 2) | lg) ^ (rd & 7);
          vf[fd] = *(const short8*)&S[vOff + rd * 64 + gv * 8];
        }
        __builtin_amdgcn_s_setprio(1);
#pragma unroll
        for (int fd = 0; fd < 4; ++fd)
          oa[fd] = __builtin_amdgcn_mfma_f32_16x16x32_bf16(pf, vf[fd], oa[fd], 0, 0, 0);
        oe = __builtin_amdgcn_mfma_f32_16x16x32_bf16(pf, ones, oe, 0, 0, 0);
        __builtin_amdgcn_s_setprio(0);
      }

      __syncthreads();
    }

#pragma unroll
    for (int r = 0; r < 4; ++r) {
      const float inv = 1.0f / oe[r];
      const size_t row = qrow0 + rowbase + r;
#pragma unroll
      for (int fd = 0; fd < 4; ++fd)
        attnb[row * 2048 + h * 64 + fd * 16 + l15] = f2bf(oa[fd][r] * inv);
    }

    if (sub == 0) {
      STAGE_Q(qts1);
      __syncthreads();
    }
  }
#undef STAGE_KV
#undef STAGE_Q
}

// ---------------------------------------------------------------------------
extern "C" void kernel_launch(void* const* d_in, const int* in_sizes, int n_in,
                              void* d_out, int out_size, void* d_ws, size_t ws_size,
                              hipStream_t stream) {
  (void)in_sizes; (void)n_in; (void)out_size; (void)ws_size;
  const float* x  = (const float*)d_in[0];
  const float* Wq = (const float*)d_in[1];
  const float* Wk = (const float*)d_in[2];
  const float* Wv = (const float*)d_in[3];
  const float* Wp = (const float*)d_in[4];

  // workspace layout (100 MiB total):
  //   [0,16M)        xb (x bf16)          -> qb (16M) overlays after QKV GEMM
  //   [16M,28M)      Wt ([Wq*qs|Wk|Wv]^T) -> kb (4M) overlays after QKV GEMM
  //   [28M,36M)      Wpt (Wp^T)            (live until proj)
  //   [36M,76M)      qkf f32 [4096][2560]  (dead after rope)
  //   [76M,80M)      vt  bf16 [(b*8+kvh)*64+d][1024]
  //   [80M,96M)      attnb bf16 [4096][2048]
  //   [96M,96M+256K) rope table float2[1024][32]
  char* w = (char*)d_ws;
  unsigned short* xb    = (unsigned short*)(w);
  unsigned short* Wt    = (unsigned short*)(w + 16777216);
  unsigned short* Wpt   = (unsigned short*)(w + 29360128);
  float*          qkf   = (float*)(w + 37748736);
  unsigned short* vtb   = (unsigned short*)(w + 79691776);
  unsigned short* attnb = (unsigned short*)(w + 83886080);
  float2*         rtab  = (float2*)(w + 100663296);
  unsigned short* qb    = (unsigned short*)(w);             // overlays xb
  unsigned short* kbuf  = (unsigned short*)(w + 16777216);  // overlays Wt
  float* out = (float*)d_out;

  rope_tab_kernel<<<128, 256, 0, stream>>>(rtab);
  cvt_bf16_kernel<<<8192, 256, 0, stream>>>(x, xb, 2097152);
  // fused Wq/Wk/Wv transpose (Q scale log2e/8 folded into Wq)
  transpose_qkv_w_kernel<<<dim3(64, 64, 3), 256, 0, stream>>>(Wq, Wk, Wv, Wt);
  transpose_bf16_kernel<<<dim3(64, 64), 256, 0, stream>>>(Wp, Wpt, 2048, 0, 1.0f);

  // QKV projection (f32 Q/K epilogue + bf16 V transpose)
  gemm256_qkv_kernel<<<dim3(12, 16), 512, 0, stream>>>(xb, Wt, qkf, vtb);
  // wide table-based RoPE: qkf f32 -> qb/kb bf16 (overwrites xb/Wt regions)
  rope_cvt2_kernel<<<5120, 256, 0, stream>>>(rtab, qkf, qb, kbuf);
  // flash attention (paired q-tiles: uniform 17 tiles/block)
  attn_mfma_kernel<<<dim3(8, 32, 4), 256, 0, stream>>>(qb, kbuf, vtb, attnb);
  // output projection: [4096][2048] x [2048][2048] -> d_out f32
  gemm256_kernel<<<dim3(8, 16), 512, 0, stream>>>(attnb, Wpt, out, 2048, 2048);
}

// Round 17
// 177.250 us; speedup vs baseline: 1.1130x; 1.1130x over previous
//
#include <hip/hip_runtime.h>
#include <hip/hip_bf16.h>

// ---------------------------------------------------------------------------
// SelfAttention fused pipeline for MI355X (gfx950)
//   QKV GEMM 256x256 8-phase (f32 Q/K + bf16 V^T epilogue); wide table RoPE;
//   bf16 MFMA attention (no-max log2 softmax); projection GEMM 256x128
//   (R17: full 256-block fill, ~half t_block).
// ---------------------------------------------------------------------------

typedef __attribute__((ext_vector_type(4))) float f32x4;
typedef __attribute__((ext_vector_type(8))) short short8;

#define AS1C(p) ((const __attribute__((address_space(1))) void*)(p))
#define AS3(p)  ((__attribute__((address_space(3))) void*)(p))

__device__ __forceinline__ unsigned short f2bf(float f) {
  union { float f; unsigned int u; } x; x.f = f;
  unsigned int r = x.u + 0x7FFFu + ((x.u >> 16) & 1u);
  return (unsigned short)(r >> 16);
}

__device__ __forceinline__ unsigned short bfc(float f) {
  return __bfloat16_as_ushort(__float2bfloat16(f));
}

__device__ __forceinline__ float ex2(float x) {
  return __builtin_amdgcn_exp2f(x);
}

// -------------------- RoPE table: tab[t*32+i] = (cos, sin) ------------------
__global__ void rope_tab_kernel(float2* __restrict__ tab) {
  const int idx = blockIdx.x * 256 + threadIdx.x;  // 32768
  const int t = idx >> 5, i = idx & 31;
  const float invf = exp2f(-(float)i * 0.41524101186092029f);
  float sv, cv;
  __sincosf((float)t * invf, &sv, &cv);
  tab[idx] = make_float2(cv, sv);
}

// -------------------- x : f32 -> bf16 (vectorized) -------------------------
__global__ void cvt_bf16_kernel(const float* __restrict__ src,
                                unsigned short* __restrict__ dst, int n4) {
  int i = blockIdx.x * blockDim.x + threadIdx.x;
  if (i >= n4) return;
  const f32x4 v = *(const f32x4*)(src + (size_t)i * 4);
  ushort4 u = make_ushort4(f2bf(v[0]), f2bf(v[1]), f2bf(v[2]), f2bf(v[3]));
  *(ushort4*)(dst + (size_t)i * 4) = u;
}

// ---- fused W transpose for Wq|Wk|Wv -> Wt [3072][2048], z selects matrix ---
__global__ void transpose_qkv_w_kernel(const float* __restrict__ Wq,
                                       const float* __restrict__ Wk,
                                       const float* __restrict__ Wv,
                                       unsigned short* __restrict__ dst) {
  __shared__ float tile[32][33];
  const int z = blockIdx.z;
  const float* src;
  int N, rowOff;
  float scale;
  if (z == 0)      { src = Wq; N = 2048; rowOff = 0;    scale = 0.18033688011112042f; }
  else if (z == 1) { src = Wk; N = 512;  rowOff = 2048; scale = 1.0f; }
  else             { src = Wv; N = 512;  rowOff = 2560; scale = 1.0f; }
  const int n0 = blockIdx.x * 32, k0 = blockIdx.y * 32;
  if (n0 >= N) return;
  const int tx = threadIdx.x & 31, ty = threadIdx.x >> 5;
#pragma unroll
  for (int i = ty; i < 32; i += 8)
    tile[i][tx] = src[(size_t)(k0 + i) * N + (n0 + tx)];
  __syncthreads();
#pragma unroll
  for (int i = ty; i < 32; i += 8)
    dst[(size_t)(rowOff + n0 + i) * 2048 + (k0 + tx)] = f2bf(tile[tx][i] * scale);
}

// -- W transpose+convert: dst[(rowOff+n)*2048+k] = bf16(src[k*N+n]*s) --------
__global__ void transpose_bf16_kernel(const float* __restrict__ src,
                                      unsigned short* __restrict__ dst,
                                      int N, int rowOff, float scale) {
  __shared__ float tile[32][33];
  const int n0 = blockIdx.x * 32, k0 = blockIdx.y * 32;
  const int tx = threadIdx.x & 31, ty = threadIdx.x >> 5;
#pragma unroll
  for (int i = ty; i < 32; i += 8)
    tile[i][tx] = src[(size_t)(k0 + i) * N + (n0 + tx)];
  __syncthreads();
#pragma unroll
  for (int i = ty; i < 32; i += 8)
    dst[(size_t)(rowOff + n0 + i) * 2048 + (k0 + tx)] = f2bf(tile[tx][i] * scale);
}

// ---- wide RoPE: reads qkf f32 [4096][2560], writes bf16 qb/kb --------------
__global__ void rope_cvt2_kernel(const float2* __restrict__ tab,
                                 const float* __restrict__ qkf,
                                 unsigned short* __restrict__ qb,
                                 unsigned short* __restrict__ kb) {
  const int idx = blockIdx.x * 256 + threadIdx.x;  // 4096*320
  const int m = idx / 320;
  const int p = idx - m * 320;
  const int t = m & 1023;
  unsigned short* dst;
  int srcCol, dcol;
  if (p < 256) { dcol = p * 8; srcCol = dcol; dst = qb + (size_t)m * 2048 + dcol; }
  else         { dcol = (p - 256) * 8; srcCol = 2048 + dcol; dst = kb + (size_t)m * 512 + dcol; }
  const int i0 = (srcCol & 63) >> 1;
  const float* src = qkf + (size_t)m * 2560 + srcCol;
  const f32x4 v0 = *(const f32x4*)(src);
  const f32x4 v1 = *(const f32x4*)(src + 4);
  float x[8] = {v0[0], v0[1], v0[2], v0[3], v1[0], v1[1], v1[2], v1[3]};
  short8 o;
#pragma unroll
  for (int j = 0; j < 4; ++j) {
    const float2 cs = tab[t * 32 + i0 + j];
    const float x1 = x[2 * j], x2 = x[2 * j + 1];
    o[2 * j]     = (short)bfc(x1 * cs.x - x2 * cs.y);
    o[2 * j + 1] = (short)bfc(x2 * cs.x + x1 * cs.y);
  }
  *(short8*)dst = o;
}

// ======================= shared 256x256 8-phase GEMM core ===================
#define GEMM_CORE(A_, Bt_, K_)                                                           \
  __shared__ unsigned short S[65536];                                                    \
  const int tid = threadIdx.x;                                                           \
  const int lane = tid & 63, w = tid >> 6;                                               \
  const int l15 = lane & 15, lg = lane >> 4;                                             \
  const int nwgx = gridDim.x;                                                            \
  const int nwg = nwgx * gridDim.y;                                                      \
  int lid = blockIdx.x + nwgx * blockIdx.y;                                              \
  lid = (lid & 7) * (nwg >> 3) + (lid >> 3);                                             \
  const int m0 = (lid / nwgx) * 256, n0 = (lid % nwgx) * 256;                            \
  const int ah = w >> 2;                                                                 \
  const int bh = (w & 3) >> 1;                                                           \
  const int bs = (w & 1) * 64;                                                           \
  const int NT = (K_) >> 6;                                                              \
  const int sr = tid >> 3;                                                               \
  const int sc = ((tid & 7) ^ (sr & 7)) << 3;                                            \
  f32x4 acc[8][4];                                                                       \
  _Pragma("unroll") for (int i = 0; i < 8; ++i)                                          \
  _Pragma("unroll") for (int j = 0; j < 4; ++j)                                          \
  _Pragma("unroll") for (int c = 0; c < 4; ++c) acc[i][j][c] = 0.f;                      \
  SB(0, 0); SB(0, 1); SA(0, 0); SA(0, 1);                                                \
  SB(1, 0); SB(1, 1); SA(1, 0); SA(1, 1);                                                \
  asm volatile("s_waitcnt vmcnt(8)" ::: "memory");                                       \
  __builtin_amdgcn_s_barrier();                                                          \
  short8 af[2][4], b0[2][2], b1[2][2];                                                   \
  for (int t = 0; t < NT; t += 2) {                                                      \
    const bool nl = (t + 2 < NT);                                                        \
    RDA(t, 0); RDB(b0, t, 0);                                                            \
    BAR();                                                                               \
    MM(0, 0, b0);                                                                        \
    BAR();                                                                               \
    RDB(b1, t, 1);                                                                       \
    BAR();                                                                               \
    MM(0, 1, b1);                                                                        \
    BAR();                                                                               \
    RDA(t, 1);                                                                           \
    if (nl) SB(t + 2, 0);                                                                \
    BAR();                                                                               \
    MM(1, 1, b1);                                                                        \
    BAR();                                                                               \
    if (nl) {                                                                            \
      SB(t + 2, 1); SA(t + 2, 0);                                                        \
      asm volatile("s_waitcnt vmcnt(6)" ::: "memory");                                   \
    } else {                                                                             \
      asm volatile("s_waitcnt vmcnt(0)" ::: "memory");                                   \
    }                                                                                    \
    BAR();                                                                               \
    MM(1, 0, b0);                                                                        \
    BAR();                                                                               \
    RDA(t + 1, 0); RDB(b0, t + 1, 0);                                                    \
    if (nl) SA(t + 2, 1);                                                                \
    BAR();                                                                               \
    MM(0, 0, b0);                                                                        \
    BAR();                                                                               \
    RDB(b1, t + 1, 1);                                                                   \
    BAR();                                                                               \
    MM(0, 1, b1);                                                                        \
    BAR();                                                                               \
    RDA(t + 1, 1);                                                                       \
    if (nl) SB(t + 3, 0);                                                                \
    BAR();                                                                               \
    MM(1, 1, b1);                                                                        \
    BAR();                                                                               \
    if (nl) {                                                                            \
      SB(t + 3, 1); SA(t + 3, 0); SA(t + 3, 1);                                          \
      asm volatile("s_waitcnt vmcnt(8)" ::: "memory");                                   \
    }                                                                                    \
    BAR();                                                                               \
    MM(1, 0, b0);                                                                        \
    BAR();                                                                               \
  }

#define SA(tile, half)                                                                   \
  do {                                                                                   \
    const unsigned short* p_ = Ap + (size_t)(m0 + (half) * 128 + sr) * Kd + (tile) * 64 + sc; \
    const int d_ = (((tile) & 1) << 14) + ((half) << 13) + tid * 8;                      \
    __builtin_amdgcn_global_load_lds(AS1C(p_), AS3(&S[d_]), 16, 0, 0);                   \
    __builtin_amdgcn_global_load_lds(AS1C(p_ + (size_t)64 * Kd), AS3(&S[d_ + 4096]), 16, 0, 0); \
  } while (0)

#define SB(tile, half)                                                                   \
  do {                                                                                   \
    const unsigned short* p_ = Bp + (size_t)(n0 + (half) * 128 + sr) * Kd + (tile) * 64 + sc; \
    const int d_ = 32768 + (((tile) & 1) << 14) + ((half) << 13) + tid * 8;              \
    __builtin_amdgcn_global_load_lds(AS1C(p_), AS3(&S[d_]), 16, 0, 0);                   \
    __builtin_amdgcn_global_load_lds(AS1C(p_ + (size_t)64 * Kd), AS3(&S[d_ + 4096]), 16, 0, 0); \
  } while (0)

#define RDA(tile, Msub)                                                                  \
  _Pragma("unroll") for (int kk = 0; kk < 2; ++kk)                                       \
  _Pragma("unroll") for (int fm = 0; fm < 4; ++fm) {                                     \
    const int r_ = (Msub) * 64 + fm * 16 + l15;                                          \
    af[kk][fm] = *(const short8*)&S[(((tile) & 1) << 14) + (ah << 13) + r_ * 64 +        \
                                    (((kk << 2) | lg) ^ (r_ & 7)) * 8];                  \
  }

#define RDB(dst, tile, Nsub)                                                             \
  _Pragma("unroll") for (int kk = 0; kk < 2; ++kk)                                       \
  _Pragma("unroll") for (int j = 0; j < 2; ++j) {                                        \
    const int r_ = bs + ((Nsub) * 2 + j) * 16 + l15;                                     \
    dst[kk][j] = *(const short8*)&S[32768 + (((tile) & 1) << 14) + (bh << 13) + r_ * 64 +\
                                    (((kk << 2) | lg) ^ (r_ & 7)) * 8];                  \
  }

#define MM(Msub, Nsub, bb)                                                               \
  do {                                                                                   \
    __builtin_amdgcn_s_setprio(1);                                                       \
    _Pragma("unroll") for (int kk = 0; kk < 2; ++kk)                                     \
    _Pragma("unroll") for (int fm = 0; fm < 4; ++fm)                                     \
    _Pragma("unroll") for (int j = 0; j < 2; ++j)                                        \
      acc[(Msub) * 4 + fm][(Nsub) * 2 + j] = __builtin_amdgcn_mfma_f32_16x16x32_bf16(    \
          af[kk][fm], bb[kk][j], acc[(Msub) * 4 + fm][(Nsub) * 2 + j], 0, 0, 0);         \
    __builtin_amdgcn_s_setprio(0);                                                       \
  } while (0)

#define BAR() __builtin_amdgcn_s_barrier()

// ---------- QKV GEMM: f32 Q/K (coalesced) + bf16 V^T ------------------------
__global__ __launch_bounds__(512, 2) void gemm256_qkv_kernel(
    const unsigned short* __restrict__ Ap, const unsigned short* __restrict__ Bp,
    float* __restrict__ qkf, unsigned short* __restrict__ vt) {
  const int Kd = 2048;
  GEMM_CORE(Ap, Bp, Kd)

  const int colbase = n0 + (w & 3) * 64;
  if (n0 >= 2560) {
#pragma unroll
    for (int fm8 = 0; fm8 < 8; ++fm8) {
      const int row = m0 + ah * 128 + (fm8 >> 2) * 64 + (fm8 & 3) * 16 + lg * 4;
      const int z = (row >> 10) * 8 + ((colbase - 2560) >> 6);
      const int t0 = row & 1023;
#pragma unroll
      for (int fn4 = 0; fn4 < 4; ++fn4) {
        const int d = (colbase + fn4 * 16 + l15 - 2560) & 63;
        ushort4 u = make_ushort4(bfc(acc[fm8][fn4][0]), bfc(acc[fm8][fn4][1]),
                                 bfc(acc[fm8][fn4][2]), bfc(acc[fm8][fn4][3]));
        *(ushort4*)&vt[(size_t)z * 65536 + d * 1024 + t0] = u;
      }
    }
  } else {
#pragma unroll
    for (int fm8 = 0; fm8 < 8; ++fm8) {
      const int row = m0 + ah * 128 + (fm8 >> 2) * 64 + (fm8 & 3) * 16 + lg * 4;
#pragma unroll
      for (int fn4 = 0; fn4 < 4; ++fn4) {
        const size_t base = (size_t)row * 2560 + colbase + fn4 * 16 + l15;
#pragma unroll
        for (int r = 0; r < 4; ++r) qkf[base + (size_t)r * 2560] = acc[fm8][fn4][r];
      }
    }
  }
}

// ============ 256x128 GEMM (projection): 8 waves 2Mx4N (32-col strips) ======
// LDS 96 KiB: A dbuf 2x16384 @0, B dbuf 2x8192 @32768 (shorts).
// 4 phases / 2 K-tiles; staging >=1 barrier after region's last reader;
// gates: end-P2 vmcnt(4) (retires prev-P4 + P1), end-P4 vmcnt(4) (P2+P3).
#define SA2(tile, half)                                                                  \
  do {                                                                                   \
    const unsigned short* p_ = Ap + (size_t)(m0 + (half) * 128 + sr) * Kd + (tile) * 64 + sc; \
    const int d_ = (((tile) & 1) << 14) + ((half) << 13) + tid * 8;                      \
    __builtin_amdgcn_global_load_lds(AS1C(p_), AS3(&S[d_]), 16, 0, 0);                   \
    __builtin_amdgcn_global_load_lds(AS1C(p_ + (size_t)64 * Kd), AS3(&S[d_ + 4096]), 16, 0, 0); \
  } while (0)

#define SB2(tile)                                                                        \
  do {                                                                                   \
    const unsigned short* p_ = Bp + (size_t)(n0 + sr) * Kd + (tile) * 64 + sc;           \
    const int d_ = 32768 + (((tile) & 1) << 13) + tid * 8;                               \
    __builtin_amdgcn_global_load_lds(AS1C(p_), AS3(&S[d_]), 16, 0, 0);                   \
    __builtin_amdgcn_global_load_lds(AS1C(p_ + (size_t)64 * Kd), AS3(&S[d_ + 4096]), 16, 0, 0); \
  } while (0)

#define RDA2(tile, Msub)                                                                 \
  _Pragma("unroll") for (int kk = 0; kk < 2; ++kk)                                       \
  _Pragma("unroll") for (int fm = 0; fm < 4; ++fm) {                                     \
    const int r_ = (Msub) * 64 + fm * 16 + l15;                                          \
    af[kk][fm] = *(const short8*)&S[(((tile) & 1) << 14) + (ah << 13) + r_ * 64 +        \
                                    (((kk << 2) | lg) ^ (r_ & 7)) * 8];                  \
  }

#define RDB2(dst, tile)                                                                  \
  _Pragma("unroll") for (int kk = 0; kk < 2; ++kk)                                       \
  _Pragma("unroll") for (int j = 0; j < 2; ++j) {                                        \
    const int r_ = wn + j * 16 + l15;                                                    \
    dst[kk][j] = *(const short8*)&S[32768 + (((tile) & 1) << 13) + r_ * 64 +             \
                                    (((kk << 2) | lg) ^ (r_ & 7)) * 8];                  \
  }

#define MM2(Msub, bb)                                                                    \
  do {                                                                                   \
    __builtin_amdgcn_s_setprio(1);                                                       \
    _Pragma("unroll") for (int kk = 0; kk < 2; ++kk)                                     \
    _Pragma("unroll") for (int fm = 0; fm < 4; ++fm)                                     \
    _Pragma("unroll") for (int j = 0; j < 2; ++j)                                        \
      acc[(Msub) * 4 + fm][j] = __builtin_amdgcn_mfma_f32_16x16x32_bf16(                 \
          af[kk][fm], bb[kk][j], acc[(Msub) * 4 + fm][j], 0, 0, 0);                      \
    __builtin_amdgcn_s_setprio(0);                                                       \
  } while (0)

__global__ __launch_bounds__(512, 1) void gemm256x128_kernel(
    const unsigned short* __restrict__ Ap, const unsigned short* __restrict__ Bp,
    float* __restrict__ C, int K, int N) {
  __shared__ unsigned short S[49152];  // 96 KiB
  const int tid = threadIdx.x;
  const int lane = tid & 63, w = tid >> 6;
  const int l15 = lane & 15, lg = lane >> 4;
  const int nwgx = gridDim.x;  // N/128
  const int nwg = nwgx * gridDim.y;
  int lid = blockIdx.x + nwgx * blockIdx.y;
  lid = (lid & 7) * (nwg >> 3) + (lid >> 3);
  const int m0 = (lid / nwgx) * 256, n0 = (lid % nwgx) * 128;
  const int ah = w >> 2;        // A half (M)
  const int wn = (w & 3) * 32;  // wave's 32-col strip
  const int NT = K >> 6;
  const int Kd = K;
  const int sr = tid >> 3;
  const int sc = ((tid & 7) ^ (sr & 7)) << 3;

  f32x4 acc[8][2];
#pragma unroll
  for (int i = 0; i < 8; ++i)
#pragma unroll
    for (int j = 0; j < 2; ++j)
#pragma unroll
      for (int c = 0; c < 4; ++c) acc[i][j][c] = 0.f;

  // prologue: B(0), A(0)h0, A(0)h1, B(1), A(1)h0 ; gate tile 0 (retire 6 of 10)
  SB2(0); SA2(0, 0); SA2(0, 1); SB2(1); SA2(1, 0);
  asm volatile("s_waitcnt vmcnt(4)" ::: "memory");
  __builtin_amdgcn_s_barrier();

  short8 af[2][4], b0[2][2], b1[2][2];

  for (int t = 0; t < NT; t += 2) {
    const bool nl = (t + 2 < NT);
    // P1: reads A(t)h0, B(t); stages A(t+1)h1 (region free since round t-2)
    RDA2(t, 0); RDB2(b0, t);
    SA2(t + 1, 1);
    BAR();
    MM2(0, b0);
    BAR();
    // P2: reads A(t)h1; stages B(t+2), A(t+2)h0; gate (retire prev-P4 + P1)
    RDA2(t, 1);
    if (nl) {
      SB2(t + 2); SA2(t + 2, 0);
      asm volatile("s_waitcnt vmcnt(4)" ::: "memory");
    } else {
      asm volatile("s_waitcnt vmcnt(0)" ::: "memory");
    }
    BAR();
    MM2(1, b0);
    BAR();
    // P3: reads A(t+1)h0, B(t+1); stages A(t+2)h1
    RDA2(t + 1, 0); RDB2(b1, t + 1);
    if (nl) SA2(t + 2, 1);
    BAR();
    MM2(0, b1);
    BAR();
    // P4: reads A(t+1)h1; stages B(t+3), A(t+3)h0; gate (retire P2 + P3)
    RDA2(t + 1, 1);
    if (nl) {
      SB2(t + 3); SA2(t + 3, 0);
      asm volatile("s_waitcnt vmcnt(4)" ::: "memory");
    }
    BAR();
    MM2(1, b1);
    BAR();
  }

  // epilogue: coalesced f32 stores
#pragma unroll
  for (int fm8 = 0; fm8 < 8; ++fm8)
#pragma unroll
    for (int j = 0; j < 2; ++j) {
      const size_t base =
          (size_t)(m0 + ah * 128 + (fm8 >> 2) * 64 + (fm8 & 3) * 16 + lg * 4) * N +
          (n0 + wn + j * 16 + l15);
#pragma unroll
      for (int r = 0; r < 4; ++r) C[base + (size_t)r * N] = acc[fm8][j][r];
    }
}

// -------------------- bf16 MFMA flash attention (causal, GQA 4:1) -----------
__global__ __launch_bounds__(256) void attn_mfma_kernel(
    const unsigned short* __restrict__ qb, const unsigned short* __restrict__ kb,
    const unsigned short* __restrict__ vt, unsigned short* __restrict__ attnb) {
  int lid = blockIdx.x + 8 * (blockIdx.y + 32 * blockIdx.z);  // 1024 blocks
  lid = (lid & 7) * 128 + (lid >> 3);                         // bijective chunk
  const int bx = lid & 7, h = (lid >> 3) & 31, b = lid >> 8;
  const int kvh = h >> 2;
  __shared__ unsigned short S[20480];  // 40 KiB
  const int tid = threadIdx.x, lane = tid & 63, w = tid >> 6;
  const int l15 = lane & 15, lg = lane >> 4;
  const int rowbase = w * 16 + lg * 4;

  const int gi0 = w * 64 + lane;
  const int r0 = gi0 >> 3, g0 = (gi0 & 7) ^ (r0 & 7);
  const int gi1 = (4 + w) * 64 + lane;
  const int r1 = gi1 >> 3, g1 = (gi1 & 7) ^ (r1 & 7);

  const unsigned short* kbase = kb + (size_t)b * 1024 * 512 + kvh * 64;
  const unsigned short* vbase = vt + (size_t)(b * 8 + kvh) * 64 * 1024;

#define STAGE_KV(kOff, vOff, jj)                                                    \
  do {                                                                              \
    __builtin_amdgcn_global_load_lds(AS1C(kbase + ((jj) * 64 + r0) * 512 + g0 * 8), \
                                     AS3(&S[(kOff) + w * 512]), 16, 0, 0);          \
    __builtin_amdgcn_global_load_lds(AS1C(kbase + ((jj) * 64 + r1) * 512 + g1 * 8), \
                                     AS3(&S[(kOff) + (4 + w) * 512]), 16, 0, 0);    \
    __builtin_amdgcn_global_load_lds(AS1C(vbase + r0 * 1024 + (jj) * 64 + g0 * 8),  \
                                     AS3(&S[(vOff) + w * 512]), 16, 0, 0);          \
    __builtin_amdgcn_global_load_lds(AS1C(vbase + r1 * 1024 + (jj) * 64 + g1 * 8),  \
                                     AS3(&S[(vOff) + (4 + w) * 512]), 16, 0, 0);    \
  } while (0)

#define STAGE_Q(qt)                                                                     \
  do {                                                                                  \
    const size_t qr_ = (size_t)b * 1024 + (qt) * 64;                                    \
    __builtin_amdgcn_global_load_lds(AS1C(qb + (qr_ + r0) * 2048 + h * 64 + g0 * 8),    \
                                     AS3(&S[w * 512]), 16, 0, 0);                       \
    __builtin_amdgcn_global_load_lds(AS1C(qb + (qr_ + r1) * 2048 + h * 64 + g1 * 8),    \
                                     AS3(&S[(4 + w) * 512]), 16, 0, 0);                 \
  } while (0)

  const int qts0 = bx, qts1 = 15 - bx;

  short8 ones;
#pragma unroll
  for (int i = 0; i < 8; ++i) ones[i] = (short)0x3F80;  // bf16 1.0

  STAGE_Q(qts0);
  STAGE_KV(4096, 12288, 0);
  __syncthreads();

  int g = 0;
  for (int sub = 0; sub < 2; ++sub) {
    const int qtc = sub ? qts1 : qts0;
    const size_t qrow0 = (size_t)b * 1024 + qtc * 64;

    short8 qf[2];
#pragma unroll
    for (int kk = 0; kk < 2; ++kk) {
      const int r = w * 16 + l15;
      const int gq = ((kk << 2) | lg) ^ (r & 7);
      qf[kk] = *(const short8*)&S[r * 64 + gq * 8];
    }

    f32x4 oa[4], oe;
#pragma unroll
    for (int r = 0; r < 4; ++r) oe[r] = 0.f;
#pragma unroll
    for (int fd = 0; fd < 4; ++fd)
#pragma unroll
      for (int r = 0; r < 4; ++r) oa[fd][r] = 0.f;

    for (int j = 0; j <= qtc; ++j, ++g) {
      const int cur = g & 1;
      const int kOff = 4096 + cur * 4096;
      const int vOff = 12288 + cur * 4096;
      if (g < 16) {
        const int nj = (g + 1 <= qts0) ? g + 1 : g - qts0;
        STAGE_KV(4096 + (cur ^ 1) * 4096, 12288 + (cur ^ 1) * 4096, nj);
      }

      f32x4 sa[4];
#pragma unroll
      for (int fn = 0; fn < 4; ++fn)
#pragma unroll
        for (int r = 0; r < 4; ++r) sa[fn][r] = 0.f;
#pragma unroll
      for (int kk = 0; kk < 2; ++kk) {
        short8 kf[4];
#pragma unroll
        for (int fn = 0; fn < 4; ++fn) {
          const int rkv = fn * 16 + l15;
          const int gk = ((kk << 2) | lg) ^ (rkv & 7);
          kf[fn] = *(const short8*)&S[kOff + rkv * 64 + gk * 8];
        }
        __builtin_amdgcn_s_setprio(1);
#pragma unroll
        for (int fn = 0; fn < 4; ++fn)
          sa[fn] = __builtin_amdgcn_mfma_f32_16x16x32_bf16(qf[kk], kf[fn], sa[fn], 0, 0, 0);
        __builtin_amdgcn_s_setprio(0);
      }

      // ---- no-max softmax: P = 2^sa (masked -> 2^-inf = 0) ----
      if (j == qtc) {
#pragma unroll
        for (int r = 0; r < 4; ++r) {
          const int row = rowbase + r;
#pragma unroll
          for (int fn = 0; fn < 4; ++fn)
            if ((fn * 16 + l15) > row) sa[fn][r] = -INFINITY;
        }
      }
#pragma unroll
      for (int fn = 0; fn < 4; ++fn)
#pragma unroll
        for (int r = 0; r < 4; ++r) sa[fn][r] = ex2(sa[fn][r]);

#pragma unroll
      for (int r = 0; r < 4; ++r) {
        const int prow = rowbase + r;
#pragma unroll
        for (int fn = 0; fn < 4; ++fn) {
          const int col = fn * 16 + l15;
          const int gp = (col >> 3) ^ (prow & 7);
          S[prow * 64 + gp * 8 + (col & 7)] = bfc(sa[fn][r]);
        }
      }

#pragma unroll
      for (int kk = 0; kk < 2; ++kk) {
        const int rp = w * 16 + l15;
        const int gp = ((kk << 2) | lg) ^ (rp & 7);
        const short8 pf = *(const short8*)&S[rp * 64 + gp * 8];
        short8 vf[4];
#pragma unroll
        for (int fd = 0; fd < 4; ++fd) {
          const int rd = fd * 16 + l15;
          const int gv = ((kk << 2) | lg) ^ (rd & 7);
          vf[fd] = *(const short8*)&S[vOff + rd * 64 + gv * 8];
        }
        __builtin_amdgcn_s_setprio(1);
#pragma unroll
        for (int fd = 0; fd < 4; ++fd)
          oa[fd] = __builtin_amdgcn_mfma_f32_16x16x32_bf16(pf, vf[fd], oa[fd], 0, 0, 0);
        oe = __builtin_amdgcn_mfma_f32_16x16x32_bf16(pf, ones, oe, 0, 0, 0);
        __builtin_amdgcn_s_setprio(0);
      }

      __syncthreads();
    }

#pragma unroll
    for (int r = 0; r < 4; ++r) {
      const float inv = 1.0f / oe[r];
      const size_t row = qrow0 + rowbase + r;
#pragma unroll
      for (int fd = 0; fd < 4; ++fd)
        attnb[row * 2048 + h * 64 + fd * 16 + l15] = f2bf(oa[fd][r] * inv);
    }

    if (sub == 0) {
      STAGE_Q(qts1);
      __syncthreads();
    }
  }
#undef STAGE_KV
#undef STAGE_Q
}

// ---------------------------------------------------------------------------
extern "C" void kernel_launch(void* const* d_in, const int* in_sizes, int n_in,
                              void* d_out, int out_size, void* d_ws, size_t ws_size,
                              hipStream_t stream) {
  (void)in_sizes; (void)n_in; (void)out_size; (void)ws_size;
  const float* x  = (const float*)d_in[0];
  const float* Wq = (const float*)d_in[1];
  const float* Wk = (const float*)d_in[2];
  const float* Wv = (const float*)d_in[3];
  const float* Wp = (const float*)d_in[4];

  char* w = (char*)d_ws;
  unsigned short* xb    = (unsigned short*)(w);
  unsigned short* Wt    = (unsigned short*)(w + 16777216);
  unsigned short* Wpt   = (unsigned short*)(w + 29360128);
  float*          qkf   = (float*)(w + 37748736);
  unsigned short* vtb   = (unsigned short*)(w + 79691776);
  unsigned short* attnb = (unsigned short*)(w + 83886080);
  float2*         rtab  = (float2*)(w + 100663296);
  unsigned short* qb    = (unsigned short*)(w);             // overlays xb
  unsigned short* kbuf  = (unsigned short*)(w + 16777216);  // overlays Wt
  float* out = (float*)d_out;

  rope_tab_kernel<<<128, 256, 0, stream>>>(rtab);
  cvt_bf16_kernel<<<8192, 256, 0, stream>>>(x, xb, 2097152);
  transpose_qkv_w_kernel<<<dim3(64, 64, 3), 256, 0, stream>>>(Wq, Wk, Wv, Wt);
  transpose_bf16_kernel<<<dim3(64, 64), 256, 0, stream>>>(Wp, Wpt, 2048, 0, 1.0f);

  // QKV projection (f32 Q/K epilogue + bf16 V transpose)
  gemm256_qkv_kernel<<<dim3(12, 16), 512, 0, stream>>>(xb, Wt, qkf, vtb);
  // wide table-based RoPE: qkf f32 -> qb/kb bf16
  rope_cvt2_kernel<<<5120, 256, 0, stream>>>(rtab, qkf, qb, kbuf);
  // flash attention
  attn_mfma_kernel<<<dim3(8, 32, 4), 256, 0, stream>>>(qb, kbuf, vtb, attnb);
  // output projection: 256x128 tiles -> 256 blocks, full CU fill
  gemm256x128_kernel<<<dim3(16, 16), 512, 0, stream>>>(attnb, Wpt, out, 2048, 2048);
}

// Round 18
// 166.239 us; speedup vs baseline: 1.1867x; 1.0662x over previous
//
#include <hip/hip_runtime.h>
#include <hip/hip_bf16.h>

// ---------------------------------------------------------------------------
// SelfAttention fused pipeline for MI355X (gfx950)
//   QKV GEMM 256x192 6-phase (256 blocks = 100% CU fill; f32 Q/K + bf16 V^T
//   epilogue); wide table RoPE; bf16 MFMA attention (no-max log2 softmax);
//   projection GEMM 256x128 (256 blocks full fill).
// ---------------------------------------------------------------------------

typedef __attribute__((ext_vector_type(4))) float f32x4;
typedef __attribute__((ext_vector_type(8))) short short8;

#define AS1C(p) ((const __attribute__((address_space(1))) void*)(p))
#define AS3(p)  ((__attribute__((address_space(3))) void*)(p))

__device__ __forceinline__ unsigned short f2bf(float f) {
  union { float f; unsigned int u; } x; x.f = f;
  unsigned int r = x.u + 0x7FFFu + ((x.u >> 16) & 1u);
  return (unsigned short)(r >> 16);
}

__device__ __forceinline__ unsigned short bfc(float f) {
  return __bfloat16_as_ushort(__float2bfloat16(f));
}

__device__ __forceinline__ float ex2(float x) {
  return __builtin_amdgcn_exp2f(x);
}

// -------------------- RoPE table: tab[t*32+i] = (cos, sin) ------------------
__global__ void rope_tab_kernel(float2* __restrict__ tab) {
  const int idx = blockIdx.x * 256 + threadIdx.x;  // 32768
  const int t = idx >> 5, i = idx & 31;
  const float invf = exp2f(-(float)i * 0.41524101186092029f);
  float sv, cv;
  __sincosf((float)t * invf, &sv, &cv);
  tab[idx] = make_float2(cv, sv);
}

// -------------------- x : f32 -> bf16 (vectorized) -------------------------
__global__ void cvt_bf16_kernel(const float* __restrict__ src,
                                unsigned short* __restrict__ dst, int n4) {
  int i = blockIdx.x * blockDim.x + threadIdx.x;
  if (i >= n4) return;
  const f32x4 v = *(const f32x4*)(src + (size_t)i * 4);
  ushort4 u = make_ushort4(f2bf(v[0]), f2bf(v[1]), f2bf(v[2]), f2bf(v[3]));
  *(ushort4*)(dst + (size_t)i * 4) = u;
}

// ---- fused W transpose for Wq|Wk|Wv -> Wt [3072][2048], z selects matrix ---
__global__ void transpose_qkv_w_kernel(const float* __restrict__ Wq,
                                       const float* __restrict__ Wk,
                                       const float* __restrict__ Wv,
                                       unsigned short* __restrict__ dst) {
  __shared__ float tile[32][33];
  const int z = blockIdx.z;
  const float* src;
  int N, rowOff;
  float scale;
  if (z == 0)      { src = Wq; N = 2048; rowOff = 0;    scale = 0.18033688011112042f; }
  else if (z == 1) { src = Wk; N = 512;  rowOff = 2048; scale = 1.0f; }
  else             { src = Wv; N = 512;  rowOff = 2560; scale = 1.0f; }
  const int n0 = blockIdx.x * 32, k0 = blockIdx.y * 32;
  if (n0 >= N) return;
  const int tx = threadIdx.x & 31, ty = threadIdx.x >> 5;
#pragma unroll
  for (int i = ty; i < 32; i += 8)
    tile[i][tx] = src[(size_t)(k0 + i) * N + (n0 + tx)];
  __syncthreads();
#pragma unroll
  for (int i = ty; i < 32; i += 8)
    dst[(size_t)(rowOff + n0 + i) * 2048 + (k0 + tx)] = f2bf(tile[tx][i] * scale);
}

// -- W transpose+convert: dst[(rowOff+n)*2048+k] = bf16(src[k*N+n]*s) --------
__global__ void transpose_bf16_kernel(const float* __restrict__ src,
                                      unsigned short* __restrict__ dst,
                                      int N, int rowOff, float scale) {
  __shared__ float tile[32][33];
  const int n0 = blockIdx.x * 32, k0 = blockIdx.y * 32;
  const int tx = threadIdx.x & 31, ty = threadIdx.x >> 5;
#pragma unroll
  for (int i = ty; i < 32; i += 8)
    tile[i][tx] = src[(size_t)(k0 + i) * N + (n0 + tx)];
  __syncthreads();
#pragma unroll
  for (int i = ty; i < 32; i += 8)
    dst[(size_t)(rowOff + n0 + i) * 2048 + (k0 + tx)] = f2bf(tile[tx][i] * scale);
}

// ---- wide RoPE: reads qkf f32 [4096][2560], writes bf16 qb/kb --------------
__global__ void rope_cvt2_kernel(const float2* __restrict__ tab,
                                 const float* __restrict__ qkf,
                                 unsigned short* __restrict__ qb,
                                 unsigned short* __restrict__ kb) {
  const int idx = blockIdx.x * 256 + threadIdx.x;  // 4096*320
  const int m = idx / 320;
  const int p = idx - m * 320;
  const int t = m & 1023;
  unsigned short* dst;
  int srcCol, dcol;
  if (p < 256) { dcol = p * 8; srcCol = dcol; dst = qb + (size_t)m * 2048 + dcol; }
  else         { dcol = (p - 256) * 8; srcCol = 2048 + dcol; dst = kb + (size_t)m * 512 + dcol; }
  const int i0 = (srcCol & 63) >> 1;
  const float* src = qkf + (size_t)m * 2560 + srcCol;
  const f32x4 v0 = *(const f32x4*)(src);
  const f32x4 v1 = *(const f32x4*)(src + 4);
  float x[8] = {v0[0], v0[1], v0[2], v0[3], v1[0], v1[1], v1[2], v1[3]};
  short8 o;
#pragma unroll
  for (int j = 0; j < 4; ++j) {
    const float2 cs = tab[t * 32 + i0 + j];
    const float x1 = x[2 * j], x2 = x[2 * j + 1];
    o[2 * j]     = (short)bfc(x1 * cs.x - x2 * cs.y);
    o[2 * j + 1] = (short)bfc(x2 * cs.x + x1 * cs.y);
  }
  *(short8*)dst = o;
}

#define BAR() __builtin_amdgcn_s_barrier()

// =========== 256x192 QKV GEMM: 256 blocks, 8 waves = 4M x 2N ================
// LDS 112 KiB (shorts): A buf(par) @ par<<14 (256x64 each); B @ 32768 +
// par*12288 (192x64 each). Granule-XOR swizzle both-sides (rule #21);
// XCD-chunked block swizzle. 6 phases / 2 K-tiles (N-thirds, 16 MFMA each);
// SB unit = 64 rows (1 load/thread), SA half = 128 rows (2 loads).
// Region-hazard-audited schedule; gates vmcnt(5) at P3/P6.
#define SA3(tile, half)                                                                  \
  do {                                                                                   \
    const unsigned short* p_ = Ap + (size_t)(m0 + (half) * 128 + sr) * 2048 + (tile) * 64 + sc; \
    const int d_ = (((tile) & 1) << 14) + ((half) << 13) + tid * 8;                      \
    __builtin_amdgcn_global_load_lds(AS1C(p_), AS3(&S[d_]), 16, 0, 0);                   \
    __builtin_amdgcn_global_load_lds(AS1C(p_ + (size_t)64 * 2048), AS3(&S[d_ + 4096]), 16, 0, 0); \
  } while (0)

#define SB3(tile, u)                                                                     \
  do {                                                                                   \
    const unsigned short* p_ = Bp + (size_t)(n0 + (u) * 64 + sr) * 2048 + (tile) * 64 + sc; \
    const int d_ = 32768 + ((tile) & 1) * 12288 + (u) * 4096 + tid * 8;                  \
    __builtin_amdgcn_global_load_lds(AS1C(p_), AS3(&S[d_]), 16, 0, 0);                   \
  } while (0)

#define RDA3(tile)                                                                       \
  _Pragma("unroll") for (int kk = 0; kk < 2; ++kk)                                       \
  _Pragma("unroll") for (int fm = 0; fm < 4; ++fm) {                                     \
    const int r_ = mg * 64 + fm * 16 + l15;                                              \
    af[kk][fm] = *(const short8*)&S[(((tile) & 1) << 14) + r_ * 64 +                     \
                                    (((kk << 2) | lg) ^ (r_ & 7)) * 8];                  \
  }

#define RDB3(tile, p)                                                                    \
  _Pragma("unroll") for (int kk = 0; kk < 2; ++kk)                                       \
  _Pragma("unroll") for (int jj = 0; jj < 2; ++jj) {                                     \
    const int r_ = ng * 96 + ((p) * 2 + jj) * 16 + l15;                                  \
    bf[kk][jj] = *(const short8*)&S[32768 + ((tile) & 1) * 12288 + r_ * 64 +             \
                                    (((kk << 2) | lg) ^ (r_ & 7)) * 8];                  \
  }

#define MM3(p)                                                                           \
  do {                                                                                   \
    __builtin_amdgcn_s_setprio(1);                                                       \
    _Pragma("unroll") for (int kk = 0; kk < 2; ++kk)                                     \
    _Pragma("unroll") for (int fm = 0; fm < 4; ++fm)                                     \
    _Pragma("unroll") for (int jj = 0; jj < 2; ++jj)                                     \
      acc[fm][(p) * 2 + jj] = __builtin_amdgcn_mfma_f32_16x16x32_bf16(                   \
          af[kk][fm], bf[kk][jj], acc[fm][(p) * 2 + jj], 0, 0, 0);                       \
    __builtin_amdgcn_s_setprio(0);                                                       \
  } while (0)

__global__ __launch_bounds__(512, 1) void gemm256x192_qkv_kernel(
    const unsigned short* __restrict__ Ap, const unsigned short* __restrict__ Bp,
    float* __restrict__ qkf, unsigned short* __restrict__ vt) {
  __shared__ unsigned short S[57344];  // 112 KiB
  const int tid = threadIdx.x;
  const int lane = tid & 63, w = tid >> 6;
  const int l15 = lane & 15, lg = lane >> 4;
  int lid = blockIdx.x + 16 * blockIdx.y;          // 256 blocks
  lid = (lid & 7) * 32 + (lid >> 3);               // bijective XCD chunk
  const int m0 = (lid >> 4) * 256, n0 = (lid & 15) * 192;
  const int mg = w >> 1;   // 4 M-groups of 64 rows
  const int ng = w & 1;    // 2 N-groups of 96 cols
  const int sr = tid >> 3;
  const int sc = ((tid & 7) ^ (sr & 7)) << 3;
  const int NT = 32;       // K=2048

  f32x4 acc[4][6];
#pragma unroll
  for (int i = 0; i < 4; ++i)
#pragma unroll
    for (int j = 0; j < 6; ++j)
#pragma unroll
      for (int c = 0; c < 4; ++c) acc[i][j][c] = 0.f;

  // prologue: A(0), B(0) full; A(1), B(1)u0 (B(1)u1,u2 deferred to P1)
  SA3(0, 0); SA3(0, 1); SB3(0, 0); SB3(0, 1); SB3(0, 2);
  SA3(1, 0); SA3(1, 1); SB3(1, 0);
  asm volatile("s_waitcnt vmcnt(5)" ::: "memory");  // tile-0 data retired
  BAR();

  short8 af[2][4], bf[2][2];

  for (int t = 0; t < NT; t += 2) {
    const bool nl = (t + 2 < NT);
    // P1: read A(t), B(t)p0; stage B(t+1)u1,u2 (regions freed prev-P6)
    RDA3(t); RDB3(t, 0);
    SB3(t + 1, 1); SB3(t + 1, 2);
    BAR();
    MM3(0);
    BAR();
    // P2: read B(t)p1; stage A(t+2)h0 (A(t) fully read in P1)
    RDB3(t, 1);
    if (nl) SA3(t + 2, 0);
    BAR();
    MM3(1);
    BAR();
    // P3: read B(t)p2; stage A(t+2)h1, B(t+2)u0 (B(t)u0 freed after P2);
    //     gate: P1's B(t+1)u1,u2 retired (oldest 2 of 7 outstanding)
    RDB3(t, 2);
    if (nl) {
      SA3(t + 2, 1); SB3(t + 2, 0);
      asm volatile("s_waitcnt vmcnt(5)" ::: "memory");
    } else {
      asm volatile("s_waitcnt vmcnt(0)" ::: "memory");
    }
    BAR();
    MM3(2);
    BAR();
    // P4: read A(t+1), B(t+1)p0; stage B(t+2)u1,u2 (freed after P3)
    RDA3(t + 1); RDB3(t + 1, 0);
    if (nl) { SB3(t + 2, 1); SB3(t + 2, 2); }
    BAR();
    MM3(0);
    BAR();
    // P5: read B(t+1)p1; stage A(t+3)h0 (A(t+1) fully read in P4)
    RDB3(t + 1, 1);
    if (nl) SA3(t + 3, 0);
    BAR();
    MM3(1);
    BAR();
    // P6: read B(t+1)p2; stage A(t+3)h1, B(t+3)u0 (B(t+1)u0 freed after P5);
    //     gate: all t+2 loads retired (newest issued P4)
    RDB3(t + 1, 2);
    if (nl) {
      SA3(t + 3, 1); SB3(t + 3, 0);
      asm volatile("s_waitcnt vmcnt(5)" ::: "memory");
    }
    BAR();
    MM3(2);
    BAR();
  }

  // epilogue: per-fragment region branch (boundaries are 16-col aligned)
#pragma unroll
  for (int fn = 0; fn < 6; ++fn) {
    const int col16 = n0 + ng * 96 + fn * 16;
    if (col16 < 2560) {
      // Q/K: coalesced f32 stores
#pragma unroll
      for (int fm = 0; fm < 4; ++fm) {
        const int row = m0 + mg * 64 + fm * 16 + lg * 4;
        const size_t base = (size_t)row * 2560 + col16 + l15;
#pragma unroll
        for (int r = 0; r < 4; ++r) qkf[base + (size_t)r * 2560] = acc[fm][fn][r];
      }
    } else {
      // V: packed transposed bf16 store
      const int dz = (col16 - 2560) >> 6;
      const int d = ((col16 - 2560) & 63) + l15;
#pragma unroll
      for (int fm = 0; fm < 4; ++fm) {
        const int row = m0 + mg * 64 + fm * 16 + lg * 4;
        const int z = (row >> 10) * 8 + dz;
        const int t0 = row & 1023;
        ushort4 u = make_ushort4(bfc(acc[fm][fn][0]), bfc(acc[fm][fn][1]),
                                 bfc(acc[fm][fn][2]), bfc(acc[fm][fn][3]));
        *(ushort4*)&vt[(size_t)z * 65536 + d * 1024 + t0] = u;
      }
    }
  }
}

// ============ 256x128 GEMM (projection): 8 waves 2Mx4N (32-col strips) ======
#define SA2(tile, half)                                                                  \
  do {                                                                                   \
    const unsigned short* p_ = Ap + (size_t)(m0 + (half) * 128 + sr) * Kd + (tile) * 64 + sc; \
    const int d_ = (((tile) & 1) << 14) + ((half) << 13) + tid * 8;                      \
    __builtin_amdgcn_global_load_lds(AS1C(p_), AS3(&S[d_]), 16, 0, 0);                   \
    __builtin_amdgcn_global_load_lds(AS1C(p_ + (size_t)64 * Kd), AS3(&S[d_ + 4096]), 16, 0, 0); \
  } while (0)

#define SB2(tile)                                                                        \
  do {                                                                                   \
    const unsigned short* p_ = Bp + (size_t)(n0 + sr) * Kd + (tile) * 64 + sc;           \
    const int d_ = 32768 + (((tile) & 1) << 13) + tid * 8;                               \
    __builtin_amdgcn_global_load_lds(AS1C(p_), AS3(&S[d_]), 16, 0, 0);                   \
    __builtin_amdgcn_global_load_lds(AS1C(p_ + (size_t)64 * Kd), AS3(&S[d_ + 4096]), 16, 0, 0); \
  } while (0)

#define RDA2(tile, Msub)                                                                 \
  _Pragma("unroll") for (int kk = 0; kk < 2; ++kk)                                       \
  _Pragma("unroll") for (int fm = 0; fm < 4; ++fm) {                                     \
    const int r_ = (Msub) * 64 + fm * 16 + l15;                                          \
    af[kk][fm] = *(const short8*)&S[(((tile) & 1) << 14) + (ah << 13) + r_ * 64 +        \
                                    (((kk << 2) | lg) ^ (r_ & 7)) * 8];                  \
  }

#define RDB2(dst, tile)                                                                  \
  _Pragma("unroll") for (int kk = 0; kk < 2; ++kk)                                       \
  _Pragma("unroll") for (int j = 0; j < 2; ++j) {                                        \
    const int r_ = wn + j * 16 + l15;                                                    \
    dst[kk][j] = *(const short8*)&S[32768 + (((tile) & 1) << 13) + r_ * 64 +             \
                                    (((kk << 2) | lg) ^ (r_ & 7)) * 8];                  \
  }

#define MM2(Msub, bb)                                                                    \
  do {                                                                                   \
    __builtin_amdgcn_s_setprio(1);                                                       \
    _Pragma("unroll") for (int kk = 0; kk < 2; ++kk)                                     \
    _Pragma("unroll") for (int fm = 0; fm < 4; ++fm)                                     \
    _Pragma("unroll") for (int j = 0; j < 2; ++j)                                        \
      acc[(Msub) * 4 + fm][j] = __builtin_amdgcn_mfma_f32_16x16x32_bf16(                 \
          af[kk][fm], bb[kk][j], acc[(Msub) * 4 + fm][j], 0, 0, 0);                      \
    __builtin_amdgcn_s_setprio(0);                                                       \
  } while (0)

__global__ __launch_bounds__(512, 1) void gemm256x128_kernel(
    const unsigned short* __restrict__ Ap, const unsigned short* __restrict__ Bp,
    float* __restrict__ C, int K, int N) {
  __shared__ unsigned short S[49152];  // 96 KiB
  const int tid = threadIdx.x;
  const int lane = tid & 63, w = tid >> 6;
  const int l15 = lane & 15, lg = lane >> 4;
  const int nwgx = gridDim.x;  // N/128
  const int nwg = nwgx * gridDim.y;
  int lid = blockIdx.x + nwgx * blockIdx.y;
  lid = (lid & 7) * (nwg >> 3) + (lid >> 3);
  const int m0 = (lid / nwgx) * 256, n0 = (lid % nwgx) * 128;
  const int ah = w >> 2;
  const int wn = (w & 3) * 32;
  const int NT = K >> 6;
  const int Kd = K;
  const int sr = tid >> 3;
  const int sc = ((tid & 7) ^ (sr & 7)) << 3;

  f32x4 acc[8][2];
#pragma unroll
  for (int i = 0; i < 8; ++i)
#pragma unroll
    for (int j = 0; j < 2; ++j)
#pragma unroll
      for (int c = 0; c < 4; ++c) acc[i][j][c] = 0.f;

  SB2(0); SA2(0, 0); SA2(0, 1); SB2(1); SA2(1, 0);
  asm volatile("s_waitcnt vmcnt(4)" ::: "memory");
  __builtin_amdgcn_s_barrier();

  short8 af[2][4], b0[2][2], b1[2][2];

  for (int t = 0; t < NT; t += 2) {
    const bool nl = (t + 2 < NT);
    RDA2(t, 0); RDB2(b0, t);
    SA2(t + 1, 1);
    BAR();
    MM2(0, b0);
    BAR();
    RDA2(t, 1);
    if (nl) {
      SB2(t + 2); SA2(t + 2, 0);
      asm volatile("s_waitcnt vmcnt(4)" ::: "memory");
    } else {
      asm volatile("s_waitcnt vmcnt(0)" ::: "memory");
    }
    BAR();
    MM2(1, b0);
    BAR();
    RDA2(t + 1, 0); RDB2(b1, t + 1);
    if (nl) SA2(t + 2, 1);
    BAR();
    MM2(0, b1);
    BAR();
    RDA2(t + 1, 1);
    if (nl) {
      SB2(t + 3); SA2(t + 3, 0);
      asm volatile("s_waitcnt vmcnt(4)" ::: "memory");
    }
    BAR();
    MM2(1, b1);
    BAR();
  }

#pragma unroll
  for (int fm8 = 0; fm8 < 8; ++fm8)
#pragma unroll
    for (int j = 0; j < 2; ++j) {
      const size_t base =
          (size_t)(m0 + ah * 128 + (fm8 >> 2) * 64 + (fm8 & 3) * 16 + lg * 4) * N +
          (n0 + wn + j * 16 + l15);
#pragma unroll
      for (int r = 0; r < 4; ++r) C[base + (size_t)r * N] = acc[fm8][j][r];
    }
}

// -------------------- bf16 MFMA flash attention (causal, GQA 4:1) -----------
__global__ __launch_bounds__(256) void attn_mfma_kernel(
    const unsigned short* __restrict__ qb, const unsigned short* __restrict__ kb,
    const unsigned short* __restrict__ vt, unsigned short* __restrict__ attnb) {
  int lid = blockIdx.x + 8 * (blockIdx.y + 32 * blockIdx.z);  // 1024 blocks
  lid = (lid & 7) * 128 + (lid >> 3);                         // bijective chunk
  const int bx = lid & 7, h = (lid >> 3) & 31, b = lid >> 8;
  const int kvh = h >> 2;
  __shared__ unsigned short S[20480];  // 40 KiB
  const int tid = threadIdx.x, lane = tid & 63, w = tid >> 6;
  const int l15 = lane & 15, lg = lane >> 4;
  const int rowbase = w * 16 + lg * 4;

  const int gi0 = w * 64 + lane;
  const int r0 = gi0 >> 3, g0 = (gi0 & 7) ^ (r0 & 7);
  const int gi1 = (4 + w) * 64 + lane;
  const int r1 = gi1 >> 3, g1 = (gi1 & 7) ^ (r1 & 7);

  const unsigned short* kbase = kb + (size_t)b * 1024 * 512 + kvh * 64;
  const unsigned short* vbase = vt + (size_t)(b * 8 + kvh) * 64 * 1024;

#define STAGE_KV(kOff, vOff, jj)                                                    \
  do {                                                                              \
    __builtin_amdgcn_global_load_lds(AS1C(kbase + ((jj) * 64 + r0) * 512 + g0 * 8), \
                                     AS3(&S[(kOff) + w * 512]), 16, 0, 0);          \
    __builtin_amdgcn_global_load_lds(AS1C(kbase + ((jj) * 64 + r1) * 512 + g1 * 8), \
                                     AS3(&S[(kOff) + (4 + w) * 512]), 16, 0, 0);    \
    __builtin_amdgcn_global_load_lds(AS1C(vbase + r0 * 1024 + (jj) * 64 + g0 * 8),  \
                                     AS3(&S[(vOff) + w * 512]), 16, 0, 0);          \
    __builtin_amdgcn_global_load_lds(AS1C(vbase + r1 * 1024 + (jj) * 64 + g1 * 8),  \
                                     AS3(&S[(vOff) + (4 + w) * 512]), 16, 0, 0);    \
  } while (0)

#define STAGE_Q(qt)                                                                     \
  do {                                                                                  \
    const size_t qr_ = (size_t)b * 1024 + (qt) * 64;                                    \
    __builtin_amdgcn_global_load_lds(AS1C(qb + (qr_ + r0) * 2048 + h * 64 + g0 * 8),    \
                                     AS3(&S[w * 512]), 16, 0, 0);                       \
    __builtin_amdgcn_global_load_lds(AS1C(qb + (qr_ + r1) * 2048 + h * 64 + g1 * 8),    \
                                     AS3(&S[(4 + w) * 512]), 16, 0, 0);                 \
  } while (0)

  const int qts0 = bx, qts1 = 15 - bx;

  short8 ones;
#pragma unroll
  for (int i = 0; i < 8; ++i) ones[i] = (short)0x3F80;  // bf16 1.0

  STAGE_Q(qts0);
  STAGE_KV(4096, 12288, 0);
  __syncthreads();

  int g = 0;
  for (int sub = 0; sub < 2; ++sub) {
    const int qtc = sub ? qts1 : qts0;
    const size_t qrow0 = (size_t)b * 1024 + qtc * 64;

    short8 qf[2];
#pragma unroll
    for (int kk = 0; kk < 2; ++kk) {
      const int r = w * 16 + l15;
      const int gq = ((kk << 2) | lg) ^ (r & 7);
      qf[kk] = *(const short8*)&S[r * 64 + gq * 8];
    }

    f32x4 oa[4], oe;
#pragma unroll
    for (int r = 0; r < 4; ++r) oe[r] = 0.f;
#pragma unroll
    for (int fd = 0; fd < 4; ++fd)
#pragma unroll
      for (int r = 0; r < 4; ++r) oa[fd][r] = 0.f;

    for (int j = 0; j <= qtc; ++j, ++g) {
      const int cur = g & 1;
      const int kOff = 4096 + cur * 4096;
      const int vOff = 12288 + cur * 4096;
      if (g < 16) {
        const int nj = (g + 1 <= qts0) ? g + 1 : g - qts0;
        STAGE_KV(4096 + (cur ^ 1) * 4096, 12288 + (cur ^ 1) * 4096, nj);
      }

      f32x4 sa[4];
#pragma unroll
      for (int fn = 0; fn < 4; ++fn)
#pragma unroll
        for (int r = 0; r < 4; ++r) sa[fn][r] = 0.f;
#pragma unroll
      for (int kk = 0; kk < 2; ++kk) {
        short8 kf[4];
#pragma unroll
        for (int fn = 0; fn < 4; ++fn) {
          const int rkv = fn * 16 + l15;
          const int gk = ((kk << 2) | lg) ^ (rkv & 7);
          kf[fn] = *(const short8*)&S[kOff + rkv * 64 + gk * 8];
        }
        __builtin_amdgcn_s_setprio(1);
#pragma unroll
        for (int fn = 0; fn < 4; ++fn)
          sa[fn] = __builtin_amdgcn_mfma_f32_16x16x32_bf16(qf[kk], kf[fn], sa[fn], 0, 0, 0);
        __builtin_amdgcn_s_setprio(0);
      }

      if (j == qtc) {
#pragma unroll
        for (int r = 0; r < 4; ++r) {
          const int row = rowbase + r;
#pragma unroll
          for (int fn = 0; fn < 4; ++fn)
            if ((fn * 16 + l15) > row) sa[fn][r] = -INFINITY;
        }
      }
#pragma unroll
      for (int fn = 0; fn < 4; ++fn)
#pragma unroll
        for (int r = 0; r < 4; ++r) sa[fn][r] = ex2(sa[fn][r]);

#pragma unroll
      for (int r = 0; r < 4; ++r) {
        const int prow = rowbase + r;
#pragma unroll
        for (int fn = 0; fn < 4; ++fn) {
          const int col = fn * 16 + l15;
          const int gp = (col >> 3) ^ (prow & 7);
          S[prow * 64 + gp * 8 + (col & 7)] = bfc(sa[fn][r]);
        }
      }

#pragma unroll
      for (int kk = 0; kk < 2; ++kk) {
        const int rp = w * 16 + l15;
        const int gp = ((kk << 2) | lg) ^ (rp & 7);
        const short8 pf = *(const short8*)&S[rp * 64 + gp * 8];
        short8 vf[4];
#pragma unroll
        for (int fd = 0; fd < 4; ++fd) {
          const int rd = fd * 16 + l15;
          const int gv = ((kk << 2) | lg) ^ (rd & 7);
          vf[fd] = *(const short8*)&S[vOff + rd * 64 + gv * 8];
        }
        __builtin_amdgcn_s_setprio(1);
#pragma unroll
        for (int fd = 0; fd < 4; ++fd)
          oa[fd] = __builtin_amdgcn_mfma_f32_16x16x32_bf16(pf, vf[fd], oa[fd], 0, 0, 0);
        oe = __builtin_amdgcn_mfma_f32_16x16x32_bf16(pf, ones, oe, 0, 0, 0);
        __builtin_amdgcn_s_setprio(0);
      }

      __syncthreads();
    }

#pragma unroll
    for (int r = 0; r < 4; ++r) {
      const float inv = 1.0f / oe[r];
      const size_t row = qrow0 + rowbase + r;
#pragma unroll
      for (int fd = 0; fd < 4; ++fd)
        attnb[row * 2048 + h * 64 + fd * 16 + l15] = f2bf(oa[fd][r] * inv);
    }

    if (sub == 0) {
      STAGE_Q(qts1);
      __syncthreads();
    }
  }
#undef STAGE_KV
#undef STAGE_Q
}

// ---------------------------------------------------------------------------
extern "C" void kernel_launch(void* const* d_in, const int* in_sizes, int n_in,
                              void* d_out, int out_size, void* d_ws, size_t ws_size,
                              hipStream_t stream) {
  (void)in_sizes; (void)n_in; (void)out_size; (void)ws_size;
  const float* x  = (const float*)d_in[0];
  const float* Wq = (const float*)d_in[1];
  const float* Wk = (const float*)d_in[2];
  const float* Wv = (const float*)d_in[3];
  const float* Wp = (const float*)d_in[4];

  char* w = (char*)d_ws;
  unsigned short* xb    = (unsigned short*)(w);
  unsigned short* Wt    = (unsigned short*)(w + 16777216);
  unsigned short* Wpt   = (unsigned short*)(w + 29360128);
  float*          qkf   = (float*)(w + 37748736);
  unsigned short* vtb   = (unsigned short*)(w + 79691776);
  unsigned short* attnb = (unsigned short*)(w + 83886080);
  float2*         rtab  = (float2*)(w + 100663296);
  unsigned short* qb    = (unsigned short*)(w);             // overlays xb
  unsigned short* kbuf  = (unsigned short*)(w + 16777216);  // overlays Wt
  float* out = (float*)d_out;

  rope_tab_kernel<<<128, 256, 0, stream>>>(rtab);
  cvt_bf16_kernel<<<8192, 256, 0, stream>>>(x, xb, 2097152);
  transpose_qkv_w_kernel<<<dim3(64, 64, 3), 256, 0, stream>>>(Wq, Wk, Wv, Wt);
  transpose_bf16_kernel<<<dim3(64, 64), 256, 0, stream>>>(Wp, Wpt, 2048, 0, 1.0f);

  // QKV projection: 256x192 tiles -> 256 blocks, 100% CU fill, single round
  gemm256x192_qkv_kernel<<<dim3(16, 16), 512, 0, stream>>>(xb, Wt, qkf, vtb);
  // wide table-based RoPE: qkf f32 -> qb/kb bf16
  rope_cvt2_kernel<<<5120, 256, 0, stream>>>(rtab, qkf, qb, kbuf);
  // flash attention
  attn_mfma_kernel<<<dim3(8, 32, 4), 256, 0, stream>>>(qb, kbuf, vtb, attnb);
  // output projection: 256x128 tiles -> 256 blocks, full CU fill
  gemm256x128_kernel<<<dim3(16, 16), 512, 0, stream>>>(attnb, Wpt, out, 2048, 2048);
}